// Round 12
// baseline (384.934 us; speedup 1.0000x reference)
//
#include <hip/hip_runtime.h>
#include <stdint.h>
#include <math.h>

typedef __attribute__((ext_vector_type(8))) short short8;
typedef __attribute__((ext_vector_type(4))) short short4v;
typedef __attribute__((ext_vector_type(4))) float floatx4;
typedef __attribute__((ext_vector_type(2))) float floatx2;
typedef __attribute__((ext_vector_type(2))) double doublex2;

#define DEV static __device__ __forceinline__

DEV float bf2f(unsigned short u){ union { unsigned int i; float f; } c; c.i = ((unsigned int)u) << 16; return c.f; }
DEV unsigned short f2bf(float f){ union { float f; unsigned int i; } c; c.f = f; unsigned int u = c.i; u += 0x7fffu + ((u >> 16) & 1u); return (unsigned short)(u >> 16); }

#if defined(__has_builtin)
#if __has_builtin(__builtin_amdgcn_global_load_lds)
#define USE_GLL 1
#endif
#if __has_builtin(__builtin_amdgcn_exp2f) && __has_builtin(__builtin_amdgcn_rcpf)
#define FAST_SILU 1
#endif
#endif
#ifndef USE_GLL
#define USE_GLL 0
#endif
#ifndef FAST_SILU
#define FAST_SILU 0
#endif

// async global->LDS, 16B per lane. ldsbase is wave-uniform; HW writes base + lane*16.
DEV void gll16(const unsigned short* g, unsigned short* ldsbase, int lane){
#if USE_GLL
  __builtin_amdgcn_global_load_lds((const __attribute__((address_space(1))) void*)g,
                                   (__attribute__((address_space(3))) void*)ldsbase, 16, 0, 0);
#else
  *(short8*)(ldsbase + lane * 8) = *(const short8*)g;
#endif
}

DEV float silu(float v){
#if FAST_SILU
  float ex = __builtin_amdgcn_exp2f(v * -1.44269504088896f);
  return v * __builtin_amdgcn_rcpf(1.f + ex);   // rcp err ~1ulp fp32, hidden by bf16 round
#else
  return v / (1.f + __expf(-v));
#endif
}

// -------- transpose tile helper: out_bf16[C][R] = in_f32[R][C] ----------------------------
DEV void transpose_tile(const float* in, unsigned short* out, int R, int C,
                        int bx, int by, int bz, int tid, unsigned short* tile)
{
  const long boff = (long)bz * (long)R * (long)C;
  in += boff; out += boff;
  const int c0 = bx * 64, r0 = by * 64;
  const int rr = tid >> 4;
  const int c4 = (tid & 15) * 4;
#pragma unroll
  for (int i = 0; i < 4; i++){
    int r = rr + i * 16;
    floatx4 v = *(const floatx4*)(in + (long)(r0 + r) * C + c0 + c4);
#pragma unroll
    for (int u = 0; u < 4; u++) tile[r * 68 + c4 + u] = f2bf(v[u]);
  }
  __syncthreads();
#pragma unroll
  for (int i = 0; i < 4; i++){
    int cc = rr + i * 16;
    short4v v;
#pragma unroll
    for (int u = 0; u < 4; u++) v[u] = (short)tile[(c4 + u) * 68 + cc];
    *(short4v*)(out + (long)(c0 + cc) * R + r0 + c4) = v;
  }
}

// -------- fused prep: 4 transposes + fold + xconv, flat block decode ----------------------
__global__ __launch_bounds__(256) void k_prep(const float* __restrict__ x,
    const float* __restrict__ choice, const float* __restrict__ w1,
    const float* __restrict__ w2, const float* __restrict__ head,
    const float* __restrict__ merge,
    unsigned short* __restrict__ xb, unsigned short* __restrict__ headT,
    unsigned short* __restrict__ mergeT, unsigned short* __restrict__ w1T,
    unsigned short* __restrict__ w2T, double* __restrict__ W64)
{
  __shared__ double buf[1536];   // 12.3 KB: transpose tile (8.7 KB) or fold hrow (12.3 KB)
  unsigned short* tile = (unsigned short*)buf;
  const int id = blockIdx.x, tid = threadIdx.x;
  if (id < 144){
    transpose_tile(head, headT, 768, 768, id % 12, id / 12, 0, tid, tile);
  } else if (id < 288){
    int l = id - 144;
    transpose_tile(merge, mergeT, 768, 768, l % 12, l / 12, 0, tid, tile);
  } else if (id < 576){
    int l = id - 288;
    transpose_tile(w1, w1T, 128, 384, l % 6, (l / 6) % 2, l / 12, tid, tile);
  } else if (id < 864){
    int l = id - 576;
    transpose_tile(w2, w2T, 384, 128, l % 2, (l / 2) % 6, l / 12, tid, tile);
  } else if (id < 1248){
    int l = id - 864;                       // 0..383, fold: 2 d's per block
    const int sub = tid >> 7, lt = tid & 127;
    const int d = l * 2 + sub;
    double* hrow = buf + sub * 768;
    for (int i = lt; i < 768; i += 128) hrow[i] = (double)head[(long)d * 768 + i];
    __syncthreads();
    for (int c = lt; c < 144; c += 128){
      int h = c / 24, e = c % 24;
      double a = 0.0;
      const double* hr = hrow + h * 128;
      const float* ch = choice + e * 128;
#pragma unroll 8
      for (int k = 0; k < 128; k++) a += hr[k] * (double)ch[k];
      W64[(long)d * 144 + c] = a;
    }
  } else {
    const long l = id - 1248;               // 0..6143
    const long i = (l * 256 + tid) * 4;
    floatx4 v = *(const floatx4*)(x + i);
    short4v o;
#pragma unroll
    for (int u = 0; u < 4; u++) o[u] = (short)f2bf(v[u]);
    *(short4v*)(xb + i) = o;
  }
}

// -------- bf16 MFMA GEMM body (BT input), 128x128 tile, BK=64; OUTF=1 -> fp32 C -----------
template<int OUTF>
DEV void gemm_body(const unsigned short* __restrict__ A, const unsigned short* __restrict__ BT,
                   unsigned short* __restrict__ C, float* __restrict__ Cf, int N, int K,
                   unsigned short* As, unsigned short* Bs, int m0, int n0, int tid)
{
  const int lane = tid & 63;
  const int w = tid >> 6;
  const int wy = w >> 1, wx = w & 1;

  floatx4 acc[4][4];
  {
    floatx4 z4 = {0.f, 0.f, 0.f, 0.f};
#pragma unroll
    for (int i = 0; i < 4; i++)
#pragma unroll
      for (int j = 0; j < 4; j++) acc[i][j] = z4;
  }

  const int rsub = lane >> 3;
  const int kcol = (lane & 7) * 8;

  for (int k0 = 0; k0 < K; k0 += 64){
#pragma unroll
    for (int i = 0; i < 4; i++){
      const int inst = w * 4 + i;
      const int rr = inst * 8 + rsub;
      gll16(A + (long)(m0 + rr) * K + k0 + kcol, &As[inst * 512], lane);
      gll16(BT + (long)(n0 + rr) * K + k0 + kcol, &Bs[inst * 512], lane);
    }
    __syncthreads();
#pragma unroll
    for (int ks = 0; ks < 2; ++ks){
      const int kb = ks * 32 + (lane >> 4) * 8;
      short8 af[4], bfr[4];
#pragma unroll
      for (int mi = 0; mi < 4; mi++) af[mi]  = *(const short8*)&As[(wy * 64 + mi * 16 + (lane & 15)) * 64 + kb];
#pragma unroll
      for (int ni = 0; ni < 4; ni++) bfr[ni] = *(const short8*)&Bs[(wx * 64 + ni * 16 + (lane & 15)) * 64 + kb];
#pragma unroll
      for (int mi = 0; mi < 4; mi++)
#pragma unroll
        for (int ni = 0; ni < 4; ni++)
          acc[mi][ni] = __builtin_amdgcn_mfma_f32_16x16x32_bf16(af[mi], bfr[ni], acc[mi][ni], 0, 0, 0);
    }
    __syncthreads();
  }

  const int ml = lane & 15;
  const int rq = (lane >> 4) * 4;
#pragma unroll
  for (int mi = 0; mi < 4; mi++){
    const int rowb = m0 + wy * 64 + mi * 16 + rq;
#pragma unroll
    for (int ni = 0; ni < 4; ni++){
      const int col = n0 + wx * 64 + ni * 16 + ml;
#pragma unroll
      for (int r = 0; r < 4; r++){
        float v = acc[mi][ni][r];
        if (OUTF) Cf[(long)(rowb + r) * N + col] = v;
        else      C[(long)(rowb + r) * N + col] = f2bf(v);
      }
    }
  }
}

// -------- gates matmul body v3: 64-row tiles, contiguous-9-col threads, reg-preloaded x ---
// Break the per-kk LDS latency chain: x transposed in LDS (xsT[row][kk], stride 36 ->
// b128-aligned, broadcast reads) preloaded to registers per 4-kk quarter; W cols tx*9..+8
// stored with per-kk stride 160 so each thread reads 4xb128+1xb64 (16B-aligned, 2-way=free).
// DS per 144 FMA: 4 + 4*5 = 24 inst (was 10 per 18 FMA). FMA order per logit unchanged
// (kk ascending) -> bit-identical logits vs R11.
DEV void gates_body(const float* __restrict__ xg, const double* __restrict__ W,
                    double* __restrict__ P, float* xsT /*64*36 f32*/, double* Ws /*32*160 f64*/,
                    int row0, int ksegIdx, int tid)
{
  const int tx = tid & 15;        // cols tx*9 .. tx*9+8
  const int ty = tid >> 4;        // rows ty*4 .. +4
  const int kseg = ksegIdx * 192;

  double acc[4][9];
#pragma unroll
  for (int i = 0; i < 4; i++)
#pragma unroll
    for (int j = 0; j < 9; j++) acc[i][j] = 0.0;

  for (int kc = 0; kc < 192; kc += 32){
    const int k0 = kseg + kc;
    // stage xsT: 16 rows x (16 lanes x 2 kk) per pass, 4 passes
    {
      const int rL = tid >> 4;          // 0..15
      const int kL = (tid & 15) * 2;    // 0,2,..,30
#pragma unroll
      for (int p = 0; p < 4; ++p){
        const int rr = p * 16 + rL;
        floatx2 v = *(const floatx2*)(xg + (long)(row0 + rr) * 768 + k0 + kL);
        *(floatx2*)&xsT[rr * 36 + kL] = v;
      }
    }
    // stage Ws[kk][(c/9)*10 + c%9] = W[k0+kk][c]
    for (int f = tid; f < 4608; f += 256){
      int kk = f / 144, c = f - kk * 144;
      int c9 = c / 9, cm = c - c9 * 9;
      Ws[kk * 160 + c9 * 10 + cm] = W[(long)(k0 + kk) * 144 + c];
    }
    __syncthreads();
#pragma unroll
    for (int q = 0; q < 8; ++q){        // 4-kk quarters, kk = q*4 + kk2 ascending
      floatx4 xr[4];
#pragma unroll
      for (int i = 0; i < 4; i++)
        xr[i] = *(const floatx4*)&xsT[(ty * 4 + i) * 36 + q * 4];
#pragma unroll
      for (int kk2 = 0; kk2 < 4; ++kk2){
        const double* wrow = Ws + (q * 4 + kk2) * 160 + tx * 10;
        double w[9];
#pragma unroll
        for (int j2 = 0; j2 < 4; j2++){
          doublex2 wv = *(const doublex2*)(wrow + j2 * 2);
          w[j2 * 2] = wv[0]; w[j2 * 2 + 1] = wv[1];
        }
        w[8] = wrow[8];
#pragma unroll
        for (int i = 0; i < 4; i++){
          double xd = (double)xr[i][kk2];
#pragma unroll
          for (int j = 0; j < 9; j++) acc[i][j] += xd * w[j];
        }
      }
    }
    __syncthreads();
  }
  double* dstseg = P + (long)ksegIdx * 8192 * 144;
#pragma unroll
  for (int i = 0; i < 4; i++){
    double* dst = dstseg + (long)(row0 + ty * 4 + i) * 144 + tx * 9;
#pragma unroll
    for (int j = 0; j < 9; j++) dst[j] = acc[i][j];
  }
}

// -------- fused gates + head-GEMM: [0,512) gates tiles FIRST, [512,896) gemm --------------
// LDS union: gates 9216+40960 = 50176 B | gemm 32768 B -> 50176 B, 3 blocks/CU.
__global__ __launch_bounds__(256, 2) void k_main0(const unsigned short* __restrict__ xb,
    const unsigned short* __restrict__ headT, unsigned short* __restrict__ x1,
    const float* __restrict__ xg, const double* __restrict__ W, double* __restrict__ P)
{
  __shared__ double lds[6272];   // 50176 B
  const int id = blockIdx.x, tid = threadIdx.x;
  if (id < 512){
    float* xsT = (float*)lds;
    double* Ws = (double*)((char*)lds + 9216);
    gates_body(xg, W, P, xsT, Ws, (id & 127) * 64, id >> 7, tid);
  } else {
    const int id2 = id - 512;    // 0..383
    unsigned short* As = (unsigned short*)lds;
    unsigned short* Bs = As + 128 * 64;
    gemm_body<0>(xb, headT, x1, nullptr, 768, 768, As, Bs, (id2 & 63) * 128, (id2 >> 6) * 128, tid);
  }
}

// -------- fused reduce + softmax: logits from 4 partials, softmax, write gatesT[be][n] ----
__global__ __launch_bounds__(256) void k_softmax(const double* __restrict__ P,
                                                 double* __restrict__ gatesT)
{
  const int gid = blockIdx.x * 256 + threadIdx.x;   // < 49152
  const int R = gid / 6, h = gid % 6;
  const int b = R >> 10, s = R & 1023;
  const int n = s * 6 + h;
  const long S = (long)8192 * 144;
  const long base = (long)R * 144 + h * 24;
  double l[24];
#pragma unroll
  for (int e = 0; e < 24; e++){
    const long o = base + e;
    l[e] = (P[o] + P[S + o]) + (P[2 * S + o] + P[3 * S + o]);
  }
  double m = l[0];
#pragma unroll
  for (int e = 1; e < 24; e++) m = fmax(m, l[e]);
  double ssum = 0.0;
#pragma unroll
  for (int e = 0; e < 24; e++){ l[e] = exp(l[e] - m); ssum += l[e]; }
  double is = 1.0 / ssum;
#pragma unroll
  for (int e = 0; e < 24; e++)
    gatesT[((long)(b * 24 + e)) * 6144 + n] = l[e] * is;
}

// -------- top-K=1024 of 6144 per (b,e), exact fp64, jax tie semantics ---------------------
DEV int blk_reduce(int v, volatile int* sbuf, int tid){
#pragma unroll
  for (int off = 32; off > 0; off >>= 1) v += __shfl_down(v, off);
  __syncthreads();
  if ((tid & 63) == 0) sbuf[tid >> 6] = v;
  __syncthreads();
  return sbuf[0] + sbuf[1] + sbuf[2] + sbuf[3];
}

__global__ __launch_bounds__(256) void k_topk(const double* __restrict__ gatesT,
                                              int* __restrict__ Kidx, float* __restrict__ Gval,
                                              int* __restrict__ cnt, unsigned short* __restrict__ inv)
{
  __shared__ int sbuf[4];
  __shared__ int s_pos;
  const int tid = threadIdx.x;
  const int be = blockIdx.x;
  const int b = be / 24, e = be % 24;
  const double* g = gatesT + (long)be * 6144;

  unsigned long long key[24];
#pragma unroll
  for (int j = 0; j < 24; j++)
    key[j] = (unsigned long long)__double_as_longlong(g[tid + 256 * j]);

  unsigned long long lo = 0ull, hi = ~0ull;
  for (int it = 0; it < 64; ++it){
    if (hi - lo <= 1ull) break;
    unsigned long long mid = lo + ((hi - lo) >> 1);
    int c = 0;
#pragma unroll
    for (int j = 0; j < 24; j++) c += (key[j] > mid) ? 1 : 0;
    c = blk_reduce(c, sbuf, tid);
    if (c >= 1024) lo = mid; else hi = mid;
  }
  const unsigned long long T = hi;
  int cg = 0;
#pragma unroll
  for (int j = 0; j < 24; j++) cg += (key[j] > T) ? 1 : 0;
  cg = blk_reduce(cg, sbuf, tid);
  const int need = 1024 - cg;

  int lo2 = 0, hi2 = 6144;
  for (int it = 0; it < 13; ++it){
    if (hi2 - lo2 <= 1) break;
    int mid = (lo2 + hi2) >> 1;
    int c = 0;
#pragma unroll
    for (int j = 0; j < 24; j++) c += (key[j] == T && (tid + 256 * j) < mid) ? 1 : 0;
    c = blk_reduce(c, sbuf, tid);
    if (c >= need) hi2 = mid; else lo2 = mid;
  }
  const int m = hi2;

  if (tid == 0) s_pos = 0;
  __syncthreads();
#pragma unroll
  for (int j = 0; j < 24; j++){
    int n = tid + 256 * j;
    bool sel = (key[j] > T) || (key[j] == T && n < m);
    if (sel){
      int slot = atomicAdd(&s_pos, 1);
      Kidx[(long)be * 1024 + slot] = n;
      Gval[(long)be * 1024 + slot] = (float)__longlong_as_double((long long)key[j]);
      int t = b * 6144 + n;
      int p = atomicAdd(&cnt[t], 1);
      inv[(long)t * 24 + p] = (unsigned short)(e * 1024 + slot);
    }
  }
}

// -------- merge GEMM (fp32 out) -----------------------------------------------------------
__global__ __launch_bounds__(256, 2) void k_gemm2(const unsigned short* __restrict__ A,
    const unsigned short* __restrict__ BT, float* __restrict__ Cf)
{
  __shared__ unsigned short As[128 * 64];
  __shared__ unsigned short Bs[128 * 64];
  gemm_body<1>(A, BT, nullptr, Cf, 768, 768, As, Bs,
               (int)blockIdx.x * 128, (int)blockIdx.y * 128, (int)threadIdx.x);
}

// -------- fused per-expert FFN: Y[be][k][dh] = gate * (silu(gather(x1)@w1) @ w2), bf16 ----
// grid (8 m-tiles of 128 rows, 192 be). block 256. LDS exactly 80 KB -> 2 blocks/CU.
// All LDS XOR-chunk-swizzled (16B chunks): As/W1c pos = chunk^(row&15); W2c pos = chunk^(row&7);
// Hc pos = chunk^(tokrow&7).
__global__ __launch_bounds__(256, 2) void k_ffn(const unsigned short* __restrict__ x1,
    const unsigned short* __restrict__ w1T, const unsigned short* __restrict__ w2T,
    const int* __restrict__ KidxAll, const float* __restrict__ GvalAll,
    unsigned short* __restrict__ Y)
{
  __shared__ unsigned short As[128 * 128];   // 32 KB [row][k]
  __shared__ unsigned short W1c[64 * 128];   // 16 KB [hcol][k]
  __shared__ unsigned short W2c[128 * 64];   // 16 KB [out][hchunk]
  __shared__ unsigned short Hc[128 * 64];    // 16 KB [tokrow][hcol]
  const int tid = threadIdx.x, lane = tid & 63, w = tid >> 6;
  const int tx = lane & 15, quad = lane >> 4;
  const int mt = blockIdx.x;
  const int be = blockIdx.y;
  const int b = be / 24, e = be % 24;
  const int* idx = KidxAll + (long)be * 1024 + mt * 128;
  const float* scl = GvalAll + (long)be * 1024 + mt * 128;
  const unsigned short* A   = x1  + (long)b * 6144 * 128;
  const unsigned short* w1e = w1T + (long)e * 384 * 128;
  const unsigned short* w2e = w2T + (long)e * 128 * 384;

  {
    const int r0 = w * 32;
#pragma unroll
    for (int i = 0; i < 8; i++){
      int rr = r0 + i * 4 + quad;
      int c = tx ^ (rr & 15);
      gll16(A + (long)idx[rr] * 128 + c * 8, &As[(r0 + i * 4) * 128], lane);
    }
  }

  floatx4 Yt[2][8];   // [mf out-tile][nf tokrow-tile]
  {
    floatx4 z4 = {0.f, 0.f, 0.f, 0.f};
#pragma unroll
    for (int i = 0; i < 2; i++)
#pragma unroll
      for (int j = 0; j < 8; j++) Yt[i][j] = z4;
  }

  for (int nc = 0; nc < 6; ++nc){
    {
      const int r0 = w * 16;
#pragma unroll
      for (int i = 0; i < 4; i++){
        int lr = r0 + i * 4 + quad;
        int c = tx ^ (lr & 15);
        gll16(w1e + (long)(nc * 64 + lr) * 128 + c * 8, &W1c[(r0 + i * 4) * 128], lane);
      }
    }
    {
      const int r0 = w * 32;
#pragma unroll
      for (int i = 0; i < 4; i++){
        int rr = r0 + i * 8 + (lane >> 3);
        int c = (lane & 7) ^ (rr & 7);
        gll16(w2e + (long)rr * 384 + nc * 64 + c * 8, &W2c[(r0 + i * 8) * 64], lane);
      }
    }
    __syncthreads();

    // stage1: h = silu(As @ W1c^T); wave w -> rows w*32..+32 (2 mi) x 64 hcols (4 nf)
    floatx4 h4[2][4];
    {
      floatx4 z4 = {0.f, 0.f, 0.f, 0.f};
#pragma unroll
      for (int i = 0; i < 2; i++)
#pragma unroll
        for (int j = 0; j < 4; j++) h4[i][j] = z4;
    }
#pragma unroll
    for (int ks = 0; ks < 4; ++ks){
      const int chunk = ks * 4 + quad;
      const int pos = chunk ^ tx;
      short8 af[2];
#pragma unroll
      for (int mi = 0; mi < 2; ++mi)
        af[mi] = *(const short8*)&As[(w * 32 + mi * 16 + tx) * 128 + pos * 8];
#pragma unroll
      for (int nf = 0; nf < 4; ++nf){
        short8 bfr = *(const short8*)&W1c[(nf * 16 + tx) * 128 + pos * 8];
#pragma unroll
        for (int mi = 0; mi < 2; ++mi)
          h4[mi][nf] = __builtin_amdgcn_mfma_f32_16x16x32_bf16(af[mi], bfr, h4[mi][nf], 0, 0, 0);
      }
    }
#pragma unroll
    for (int mi = 0; mi < 2; ++mi){
#pragma unroll
      for (int nf = 0; nf < 4; ++nf){
        const int hchunk = nf * 2 + (tx >> 3);
        const int hoff = tx & 7;
#pragma unroll
        for (int r = 0; r < 4; r++){
          float v = silu(h4[mi][nf][r]);
          const int trow = w * 32 + mi * 16 + quad * 4 + r;
          Hc[trow * 64 + (hchunk ^ (trow & 7)) * 8 + hoff] = f2bf(v);
        }
      }
    }
    __syncthreads();

    // stage2: YT[out][tokrow] += W2c[out][hcol] x Hc[tokrow][hcol]; wave w -> outs w*32..+32
#pragma unroll
    for (int ks = 0; ks < 2; ++ks){
      const int chunk2 = ks * 4 + quad;
      const int posx = chunk2 ^ (tx & 7);
      short8 a2[2], b2[8];
#pragma unroll
      for (int mf = 0; mf < 2; ++mf)
        a2[mf] = *(const short8*)&W2c[(w * 32 + mf * 16 + tx) * 64 + posx * 8];
#pragma unroll
      for (int nf = 0; nf < 8; ++nf)
        b2[nf] = *(const short8*)&Hc[(nf * 16 + tx) * 64 + posx * 8];
#pragma unroll
      for (int mf = 0; mf < 2; ++mf)
#pragma unroll
        for (int nf = 0; nf < 8; ++nf)
          Yt[mf][nf] = __builtin_amdgcn_mfma_f32_16x16x32_bf16(a2[mf], b2[nf], Yt[mf][nf], 0, 0, 0);
    }
    __syncthreads();
  }

#pragma unroll
  for (int nf = 0; nf < 8; ++nf){
    const int rb = nf * 16 + tx;
    const float g = scl[rb];
    unsigned short* dst = Y + ((long)be * 1024 + mt * 128 + rb) * 128 + w * 32 + quad * 4;
#pragma unroll
    for (int mf = 0; mf < 2; ++mf){
      short4v v;
#pragma unroll
      for (int r = 0; r < 4; r++) v[r] = (short)f2bf(Yt[mf][nf][r] * g);
      *(short4v*)(dst + mf * 16) = v;
    }
  }
}

// -------- combine: xout[t][:] = sum over picks of Y[e][slot][:] (gates pre-applied) -------
__global__ __launch_bounds__(256) void k_combine(const int* __restrict__ cnt,
    const unsigned short* __restrict__ inv, const unsigned short* __restrict__ Y,
    unsigned short* __restrict__ xout)
{
  const int t = blockIdx.x * 4 + (threadIdx.x >> 6);   // token id, < 49152
  const int lane = threadIdx.x & 63;
  const int b = t / 6144;
  const int c = cnt[t];
  float a0 = 0.f, a1 = 0.f;
  for (int p = 0; p < c; ++p){
    int code = inv[(long)t * 24 + p];
    int e = code >> 10, slot = code & 1023;
    const unsigned short* y = Y + (((long)(b * 24 + e) * 1024 + slot) << 7) + lane * 2;
    a0 += bf2f(y[0]); a1 += bf2f(y[1]);
  }
  unsigned short* o = xout + ((long)t << 7) + lane * 2;
  o[0] = f2bf(a0); o[1] = f2bf(a1);
}

// ==========================================================================================
extern "C" void kernel_launch(void* const* d_in, const int* in_sizes, int n_in,
                              void* d_out, int out_size, void* d_ws, size_t ws_size,
                              hipStream_t stream)
{
  const float* x      = (const float*)d_in[0];
  const float* choice = (const float*)d_in[1];
  const float* w1     = (const float*)d_in[2];
  const float* w2     = (const float*)d_in[3];
  const float* head   = (const float*)d_in[4];
  const float* merge  = (const float*)d_in[5];
  float* out = (float*)d_out;
  (void)in_sizes; (void)n_in; (void)out_size; (void)ws_size;

  char* p = (char*)d_ws;
  auto alloc = [&p](size_t bytes) -> void* {
    void* q = (void*)p; p += (bytes + 255) & ~(size_t)255; return q;
  };

  unsigned short* headT = (unsigned short*)alloc((size_t)768 * 768 * 2);
  unsigned short* mergeT= (unsigned short*)alloc((size_t)768 * 768 * 2);
  unsigned short* w1T   = (unsigned short*)alloc((size_t)24 * 384 * 128 * 2);
  unsigned short* w2T   = (unsigned short*)alloc((size_t)24 * 128 * 384 * 2);
  double* W64           = (double*)alloc((size_t)768 * 144 * 8);
  int* Kidx             = (int*)alloc((size_t)192 * 1024 * 4);
  float* Gval           = (float*)alloc((size_t)192 * 1024 * 4);
  int* cnt              = (int*)alloc((size_t)49152 * 4);
  unsigned short* inv   = (unsigned short*)alloc((size_t)49152 * 24 * 2);
  unsigned short* xb    = (unsigned short*)alloc((size_t)8192 * 768 * 2);   // 12.58 MB
  unsigned short* x1    = (unsigned short*)alloc((size_t)8192 * 768 * 2);   // 12.58 MB
  // big region (50.33 MB): Y for ffn; before topk it hosts P (37.75) + gatesT (9.44)
  unsigned short* Y     = (unsigned short*)alloc((size_t)192 * 1024 * 128 * 2);
  double* P             = (double*)Y;                                             // [4][8192][144]
  double* gatesT        = (double*)((char*)Y + (size_t)4 * 8192 * 144 * 8);       // 9.44 MB
  unsigned short* xout  = xb;            // xb dead after k_main0; xout written by combine

  hipMemsetAsync(cnt, 0, (size_t)49152 * 4, stream);
  k_prep<<<dim3(7392), 256, 0, stream>>>(x, choice, w1, w2, head, merge,
                                         xb, headT, mergeT, w1T, w2T, W64);
  k_main0<<<dim3(896), 256, 0, stream>>>(xb, headT, x1, x, W64, P);
  k_softmax<<<dim3(192), 256, 0, stream>>>(P, gatesT);
  k_topk<<<dim3(192), 256, 0, stream>>>(gatesT, Kidx, Gval, cnt, inv);
  // P/gatesT dead; Y region free for ffn
  k_ffn<<<dim3(8, 192, 1), 256, 0, stream>>>(x1, w1T, w2T, Kidx, Gval, Y);
  k_combine<<<dim3(12288), 256, 0, stream>>>(cnt, inv, Y, xout);
  k_gemm2<<<dim3(64, 6, 1), 256, 0, stream>>>(xout, mergeT, out);
}